// Round 2
// baseline (5010.312 us; speedup 1.0000x reference)
//
#include <hip/hip_runtime.h>
#include <math.h>

#define NR 8
#define EB 32

__device__ __forceinline__ float silu_f(float x) {
  return x / (1.0f + __expf(-x));
}

// ---------------- node kernel: node_out + v_out ----------------
__global__ __launch_bounds__(128)
void node_kernel(const float* __restrict__ s_t,
                 const float* __restrict__ x_t,
                 const float* __restrict__ v_t,
                 const float* __restrict__ dst_lig_x,
                 const float* __restrict__ dst_lig_a,
                 const float* __restrict__ W1, const float* __restrict__ b1,
                 const float* __restrict__ W2, const float* __restrict__ b2,
                 float* __restrict__ node_out, float* __restrict__ v_out,
                 int N)
{
  __shared__ float in_s[NR][160];   // [rbf 16 | a 16 | s_t 128]
  __shared__ float h_s[NR][128];
  const int j = threadIdx.x;
  const int row0 = blockIdx.x * NR;

  // stage s_t rows (coalesced, stream-once -> nontemporal)
  #pragma unroll
  for (int r = 0; r < NR; ++r) {
    int row = row0 + r;
    if (row < N) in_s[r][32 + j] = __builtin_nontemporal_load(&s_t[(size_t)row * 128 + j]);
  }

  // rbf + dst_lig_a + v_out: 128 threads = 8 rows x 16
  {
    const int r = j >> 4, m = j & 15;
    const int row = row0 + r;
    if (row < N) {
      float ax = x_t[row*3+0], ay = x_t[row*3+1], az = x_t[row*3+2];
      float dx = dst_lig_x[row*3+0] - ax;
      float dy = dst_lig_x[row*3+1] - ay;
      float dz = dst_lig_x[row*3+2] - az;
      float d2 = fmaxf(dx*dx + dy*dy + dz*dz, 1e-8f);
      float dij = sqrtf(d2);
      // mu_m = m * 10/15, sigma = 10/16 -> 1/sigma = 1.6
      float tt = (dij - 0.66666667f * (float)m) * 1.6f;
      in_s[r][m] = __expf(-tt * tt);
      in_s[r][16 + m] = __builtin_nontemporal_load(&dst_lig_a[(size_t)row*16 + m]);
      if (m < 12) {
        float val;
        if (m < 9)       val = __builtin_nontemporal_load(&v_t[(size_t)row*12 + m]);
        else if (m == 9) val = dx / dij;
        else if (m == 10)val = dy / dij;
        else             val = dz / dij;
        __builtin_nontemporal_store(val, &v_out[(size_t)row*12 + m]);
      }
    }
  }
  __syncthreads();

  // layer 1: 160 -> 128
  float acc[NR];
  const float bb1 = b1[j];
  #pragma unroll
  for (int r = 0; r < NR; ++r) acc[r] = bb1;
  for (int k0 = 0; k0 < 160; k0 += 4) {
    float w0 = W1[(size_t)(k0+0)*128 + j];
    float w1 = W1[(size_t)(k0+1)*128 + j];
    float w2 = W1[(size_t)(k0+2)*128 + j];
    float w3 = W1[(size_t)(k0+3)*128 + j];
    #pragma unroll
    for (int r = 0; r < NR; ++r) {
      float4 a = *reinterpret_cast<const float4*>(&in_s[r][k0]);
      acc[r] = fmaf(a.x, w0, acc[r]);
      acc[r] = fmaf(a.y, w1, acc[r]);
      acc[r] = fmaf(a.z, w2, acc[r]);
      acc[r] = fmaf(a.w, w3, acc[r]);
    }
  }
  #pragma unroll
  for (int r = 0; r < NR; ++r) h_s[r][j] = silu_f(acc[r]);
  __syncthreads();

  // layer 2: 128 -> 128
  const float bb2 = b2[j];
  #pragma unroll
  for (int r = 0; r < NR; ++r) acc[r] = bb2;
  for (int k0 = 0; k0 < 128; k0 += 4) {
    float w0 = W2[(size_t)(k0+0)*128 + j];
    float w1 = W2[(size_t)(k0+1)*128 + j];
    float w2 = W2[(size_t)(k0+2)*128 + j];
    float w3 = W2[(size_t)(k0+3)*128 + j];
    #pragma unroll
    for (int r = 0; r < NR; ++r) {
      float4 a = *reinterpret_cast<const float4*>(&h_s[r][k0]);
      acc[r] = fmaf(a.x, w0, acc[r]);
      acc[r] = fmaf(a.y, w1, acc[r]);
      acc[r] = fmaf(a.z, w2, acc[r]);
      acc[r] = fmaf(a.w, w3, acc[r]);
    }
  }
  #pragma unroll
  for (int r = 0; r < NR; ++r) {
    int row = row0 + r;
    if (row < N)
      __builtin_nontemporal_store(in_s[r][32 + j] + silu_f(acc[r]),
                                  &node_out[(size_t)row*128 + j]);
  }
}

// ---------------- edge kernel: e_out (both halves) ----------------
// 4 waves x 64 lanes; wave w owns edges w*8..w*8+7; lane = output column j.
// We is read straight from global (21.7 KB, L2-resident) like node_kernel.
__global__ __launch_bounds__(256)
void edge_kernel(const float* __restrict__ e_t,
                 const float* __restrict__ x_t,
                 const float* __restrict__ dst_lig_x,
                 const float* __restrict__ dst_lig_e,
                 const int* __restrict__ edge_src,
                 const int* __restrict__ edge_dst,
                 const float* __restrict__ We, const float* __restrict__ be,
                 float* __restrict__ e_out0, float* __restrict__ e_out1,
                 int Eu)
{
  __shared__ float ein[EB][88];     // [e_u 64 | lig_e 5 | d_input 16 | 3 unused]
  __shared__ float dd[EB][2];       // [dt, d1] per edge
  const int t = threadIdx.x;
  const int e0 = blockIdx.x * EB;
  const int w = t >> 6, j = t & 63;

  // distances: 32 edges x 2 norms = 64 tasks
  if (t < 64) {
    int el = t >> 1, which = t & 1;
    int e = e0 + el;
    if (e < Eu) {
      int su = edge_src[e], du = edge_dst[e];
      const float* base = which ? dst_lig_x : x_t;
      float u0 = base[su*3+0] - base[du*3+0];
      float u1 = base[su*3+1] - base[du*3+1];
      float u2 = base[su*3+2] - base[du*3+2];
      dd[el][which] = sqrtf(fmaxf(u0*u0 + u1*u1 + u2*u2, 1e-8f));
    }
  }

  // e_u rows (coalesced, stream-once -> nontemporal)
  #pragma unroll
  for (int p = 0; p < 8; ++p) {
    int el = p*4 + w;
    int e = e0 + el;
    if (e < Eu) ein[el][j] = __builtin_nontemporal_load(&e_t[(size_t)e*64 + j]);
  }
  // dst_lig_e
  if (t < EB*5) {
    int el = t / 5, q = t % 5;
    int e = e0 + el;
    if (e < Eu) ein[el][64+q] = __builtin_nontemporal_load(&dst_lig_e[(size_t)e*5 + q]);
  }
  __syncthreads();

  // d_input = rbf(d1) - rbf(dt): 32 edges x 16 = 512 tasks, 2 passes
  #pragma unroll
  for (int p = 0; p < 2; ++p) {
    int el = p*16 + (t >> 4);
    int m  = t & 15;
    int e  = e0 + el;
    if (e < Eu) {
      float dt_ = dd[el][0], d1_ = dd[el][1];
      float mu = 0.66666667f * (float)m;
      float a1 = (d1_ - mu) * 1.6f;
      float a2 = (dt_ - mu) * 1.6f;
      ein[el][69+m] = __expf(-a1*a1) - __expf(-a2*a2);
    }
  }
  __syncthreads();

  // GEMM: wave w, lane j = column; 8 edges per lane. K = 85 = 21*4 + 1.
  float acc[8];
  const float bbe = be[j];
  #pragma unroll
  for (int e = 0; e < 8; ++e) acc[e] = bbe;
  for (int k0 = 0; k0 < 84; k0 += 4) {
    float w0 = We[(size_t)(k0+0)*64 + j];
    float w1 = We[(size_t)(k0+1)*64 + j];
    float w2 = We[(size_t)(k0+2)*64 + j];
    float w3 = We[(size_t)(k0+3)*64 + j];
    #pragma unroll
    for (int e = 0; e < 8; ++e) {
      float4 a = *reinterpret_cast<const float4*>(&ein[w*8+e][k0]);
      acc[e] = fmaf(a.x, w0, acc[e]);
      acc[e] = fmaf(a.y, w1, acc[e]);
      acc[e] = fmaf(a.z, w2, acc[e]);
      acc[e] = fmaf(a.w, w3, acc[e]);
    }
  }
  {
    float w84 = We[(size_t)84*64 + j];
    #pragma unroll
    for (int e = 0; e < 8; ++e)
      acc[e] = fmaf(ein[w*8+e][84], w84, acc[e]);
  }

  #pragma unroll
  for (int e = 0; e < 8; ++e) {
    int el = w*8 + e;
    size_t eidx = (size_t)e0 + el;
    if ((int)eidx < Eu) {
      float feat = ein[el][j] + silu_f(acc[e]);
      __builtin_nontemporal_store(feat, &e_out0[eidx*64 + j]);
      __builtin_nontemporal_store(feat, &e_out1[eidx*64 + j]);
    }
  }
}

extern "C" void kernel_launch(void* const* d_in, const int* in_sizes, int n_in,
                              void* d_out, int out_size, void* d_ws, size_t ws_size,
                              hipStream_t stream) {
  const float* s_t       = (const float*)d_in[0];
  const float* x_t       = (const float*)d_in[1];
  const float* v_t       = (const float*)d_in[2];
  const float* e_t       = (const float*)d_in[3];
  const float* dst_lig_x = (const float*)d_in[4];
  const float* dst_lig_a = (const float*)d_in[5];
  const float* dst_lig_e = (const float*)d_in[6];
  const int*   edge_src  = (const int*)d_in[7];
  const int*   edge_dst  = (const int*)d_in[8];
  const float* W1        = (const float*)d_in[9];
  const float* b1        = (const float*)d_in[10];
  const float* W2        = (const float*)d_in[11];
  const float* b2        = (const float*)d_in[12];
  const float* We        = (const float*)d_in[13];
  const float* be        = (const float*)d_in[14];

  const int N  = in_sizes[0] / 128;       // 100000
  const int Eu = in_sizes[3] / 128;       // e_t = (2*Eu, 64) -> 800000

  float* out      = (float*)d_out;
  float* node_out = out;
  float* v_out    = out + (size_t)N * 128;
  float* e_out0   = v_out + (size_t)N * 12;
  float* e_out1   = e_out0 + (size_t)Eu * 64;

  node_kernel<<<(N + NR - 1) / NR, 128, 0, stream>>>(
      s_t, x_t, v_t, dst_lig_x, dst_lig_a, W1, b1, W2, b2,
      node_out, v_out, N);

  edge_kernel<<<(Eu + EB - 1) / EB, 256, 0, stream>>>(
      e_t, x_t, dst_lig_x, dst_lig_e, edge_src, edge_dst, We, be,
      e_out0, e_out1, Eu);
}

// Round 3
// 545.496 us; speedup vs baseline: 9.1849x; 9.1849x over previous
//
#include <hip/hip_runtime.h>
#include <math.h>

#define NR 8
#define EB 32

__device__ __forceinline__ float silu_f(float x) {
  return x / (1.0f + __expf(-x));
}

// ---------------- node kernel: node_out + v_out ----------------
__global__ __launch_bounds__(128)
void node_kernel(const float* __restrict__ s_t,
                 const float* __restrict__ x_t,
                 const float* __restrict__ v_t,
                 const float* __restrict__ dst_lig_x,
                 const float* __restrict__ dst_lig_a,
                 const float* __restrict__ W1, const float* __restrict__ b1,
                 const float* __restrict__ W2, const float* __restrict__ b2,
                 float* __restrict__ node_out, float* __restrict__ v_out,
                 int N)
{
  __shared__ float in_s[NR][160];   // [rbf 16 | a 16 | s_t 128]
  __shared__ float h_s[NR][128];
  const int j = threadIdx.x;
  const int row0 = blockIdx.x * NR;

  #pragma unroll
  for (int r = 0; r < NR; ++r) {
    int row = row0 + r;
    if (row < N) in_s[r][32 + j] = __builtin_nontemporal_load(&s_t[(size_t)row * 128 + j]);
  }

  {
    const int r = j >> 4, m = j & 15;
    const int row = row0 + r;
    if (row < N) {
      float ax = x_t[row*3+0], ay = x_t[row*3+1], az = x_t[row*3+2];
      float dx = dst_lig_x[row*3+0] - ax;
      float dy = dst_lig_x[row*3+1] - ay;
      float dz = dst_lig_x[row*3+2] - az;
      float d2 = fmaxf(dx*dx + dy*dy + dz*dz, 1e-8f);
      float dij = sqrtf(d2);
      float tt = (dij - 0.66666667f * (float)m) * 1.6f;
      in_s[r][m] = __expf(-tt * tt);
      in_s[r][16 + m] = __builtin_nontemporal_load(&dst_lig_a[(size_t)row*16 + m]);
      if (m < 12) {
        float val;
        if (m < 9)       val = __builtin_nontemporal_load(&v_t[(size_t)row*12 + m]);
        else if (m == 9) val = dx / dij;
        else if (m == 10)val = dy / dij;
        else             val = dz / dij;
        __builtin_nontemporal_store(val, &v_out[(size_t)row*12 + m]);
      }
    }
  }
  __syncthreads();

  float acc[NR];
  const float bb1 = b1[j];
  #pragma unroll
  for (int r = 0; r < NR; ++r) acc[r] = bb1;
  for (int k0 = 0; k0 < 160; k0 += 4) {
    float w0 = W1[(size_t)(k0+0)*128 + j];
    float w1 = W1[(size_t)(k0+1)*128 + j];
    float w2 = W1[(size_t)(k0+2)*128 + j];
    float w3 = W1[(size_t)(k0+3)*128 + j];
    #pragma unroll
    for (int r = 0; r < NR; ++r) {
      float4 a = *reinterpret_cast<const float4*>(&in_s[r][k0]);
      acc[r] = fmaf(a.x, w0, acc[r]);
      acc[r] = fmaf(a.y, w1, acc[r]);
      acc[r] = fmaf(a.z, w2, acc[r]);
      acc[r] = fmaf(a.w, w3, acc[r]);
    }
  }
  #pragma unroll
  for (int r = 0; r < NR; ++r) h_s[r][j] = silu_f(acc[r]);
  __syncthreads();

  const float bb2 = b2[j];
  #pragma unroll
  for (int r = 0; r < NR; ++r) acc[r] = bb2;
  for (int k0 = 0; k0 < 128; k0 += 4) {
    float w0 = W2[(size_t)(k0+0)*128 + j];
    float w1 = W2[(size_t)(k0+1)*128 + j];
    float w2 = W2[(size_t)(k0+2)*128 + j];
    float w3 = W2[(size_t)(k0+3)*128 + j];
    #pragma unroll
    for (int r = 0; r < NR; ++r) {
      float4 a = *reinterpret_cast<const float4*>(&h_s[r][k0]);
      acc[r] = fmaf(a.x, w0, acc[r]);
      acc[r] = fmaf(a.y, w1, acc[r]);
      acc[r] = fmaf(a.z, w2, acc[r]);
      acc[r] = fmaf(a.w, w3, acc[r]);
    }
  }
  #pragma unroll
  for (int r = 0; r < NR; ++r) {
    int row = row0 + r;
    if (row < N)
      __builtin_nontemporal_store(in_s[r][32 + j] + silu_f(acc[r]),
                                  &node_out[(size_t)row*128 + j]);
  }
}

// ---------------- edge kernel: e_out (both halves) ----------------
// 4 waves x 64 lanes; wave w owns edges w*8..w*8+7; lane = output column j.
// launch_bounds(256,4) caps VGPR at 128; k-loop is unroll-1 to keep the
// live-set ~50 VGPRs (spill was the round-1/2 pathology: VGPR=256, 11 GB HBM).
__global__ __launch_bounds__(256, 4)
void edge_kernel(const float* __restrict__ e_t,
                 const float* __restrict__ x_t,
                 const float* __restrict__ dst_lig_x,
                 const float* __restrict__ dst_lig_e,
                 const int* __restrict__ edge_src,
                 const int* __restrict__ edge_dst,
                 const float* __restrict__ We, const float* __restrict__ be,
                 float* __restrict__ e_out0, float* __restrict__ e_out1,
                 int Eu)
{
  __shared__ float We_s[85*64];     // 21.25 KB
  __shared__ float ein[EB][88];     // [e_u 64 | lig_e 5 | d_input 16 | 3 unused]
  __shared__ float dd[EB][2];       // [dt, d1] per edge
  const int t = threadIdx.x;
  const int e0 = blockIdx.x * EB;
  const int w = t >> 6, j = t & 63;

  // stage We into LDS (coalesced; L2-resident source)
  #pragma unroll 1
  for (int i = t; i < 85*64; i += 256)
    We_s[i] = We[i];

  // distances: 32 edges x 2 norms = 64 tasks
  if (t < 64) {
    int el = t >> 1, which = t & 1;
    int e = e0 + el;
    if (e < Eu) {
      int su = edge_src[e], du = edge_dst[e];
      const float* base = which ? dst_lig_x : x_t;
      float u0 = base[su*3+0] - base[du*3+0];
      float u1 = base[su*3+1] - base[du*3+1];
      float u2 = base[su*3+2] - base[du*3+2];
      dd[el][which] = sqrtf(fmaxf(u0*u0 + u1*u1 + u2*u2, 1e-8f));
    }
  }

  // e_u rows (coalesced, stream-once -> nontemporal)
  #pragma unroll 1
  for (int p = 0; p < 8; ++p) {
    int el = p*4 + w;
    int e = e0 + el;
    if (e < Eu) ein[el][j] = __builtin_nontemporal_load(&e_t[(size_t)e*64 + j]);
  }
  // dst_lig_e
  if (t < EB*5) {
    int el = t / 5, q = t % 5;
    int e = e0 + el;
    if (e < Eu) ein[el][64+q] = __builtin_nontemporal_load(&dst_lig_e[(size_t)e*5 + q]);
  }
  __syncthreads();

  // d_input = rbf(d1) - rbf(dt): 32 edges x 16 = 512 tasks, 2 passes
  #pragma unroll 1
  for (int p = 0; p < 2; ++p) {
    int el = p*16 + (t >> 4);
    int m  = t & 15;
    int e  = e0 + el;
    if (e < Eu) {
      float dt_ = dd[el][0], d1_ = dd[el][1];
      float mu = 0.66666667f * (float)m;
      float a1 = (d1_ - mu) * 1.6f;
      float a2 = (dt_ - mu) * 1.6f;
      ein[el][69+m] = __expf(-a1*a1) - __expf(-a2*a2);
    }
  }
  __syncthreads();

  // GEMM: wave w, lane j = column; 8 edges per lane. K = 85 = 21*4 + 1.
  // unroll-1: body = 4 We_s reads + 8 broadcast b128 + 32 FMA.
  float acc[8];
  const float bbe = be[j];
  #pragma unroll
  for (int e = 0; e < 8; ++e) acc[e] = bbe;
  #pragma unroll 1
  for (int k0 = 0; k0 < 84; k0 += 4) {
    float w0 = We_s[(k0+0)*64 + j];
    float w1 = We_s[(k0+1)*64 + j];
    float w2 = We_s[(k0+2)*64 + j];
    float w3 = We_s[(k0+3)*64 + j];
    #pragma unroll
    for (int e = 0; e < 8; ++e) {
      float4 a = *reinterpret_cast<const float4*>(&ein[w*8+e][k0]);
      acc[e] = fmaf(a.x, w0, acc[e]);
      acc[e] = fmaf(a.y, w1, acc[e]);
      acc[e] = fmaf(a.z, w2, acc[e]);
      acc[e] = fmaf(a.w, w3, acc[e]);
    }
  }
  {
    float w84 = We_s[84*64 + j];
    #pragma unroll
    for (int e = 0; e < 8; ++e)
      acc[e] = fmaf(ein[w*8+e][84], w84, acc[e]);
  }

  #pragma unroll
  for (int e = 0; e < 8; ++e) {
    int el = w*8 + e;
    size_t eidx = (size_t)e0 + el;
    if ((int)eidx < Eu) {
      float feat = ein[el][j] + silu_f(acc[e]);
      __builtin_nontemporal_store(feat, &e_out0[eidx*64 + j]);
      __builtin_nontemporal_store(feat, &e_out1[eidx*64 + j]);
    }
  }
}

extern "C" void kernel_launch(void* const* d_in, const int* in_sizes, int n_in,
                              void* d_out, int out_size, void* d_ws, size_t ws_size,
                              hipStream_t stream) {
  const float* s_t       = (const float*)d_in[0];
  const float* x_t       = (const float*)d_in[1];
  const float* v_t       = (const float*)d_in[2];
  const float* e_t       = (const float*)d_in[3];
  const float* dst_lig_x = (const float*)d_in[4];
  const float* dst_lig_a = (const float*)d_in[5];
  const float* dst_lig_e = (const float*)d_in[6];
  const int*   edge_src  = (const int*)d_in[7];
  const int*   edge_dst  = (const int*)d_in[8];
  const float* W1        = (const float*)d_in[9];
  const float* b1        = (const float*)d_in[10];
  const float* W2        = (const float*)d_in[11];
  const float* b2        = (const float*)d_in[12];
  const float* We        = (const float*)d_in[13];
  const float* be        = (const float*)d_in[14];

  const int N  = in_sizes[0] / 128;       // 100000
  const int Eu = in_sizes[3] / 128;       // e_t = (2*Eu, 64) -> 800000

  float* out      = (float*)d_out;
  float* node_out = out;
  float* v_out    = out + (size_t)N * 128;
  float* e_out0   = v_out + (size_t)N * 12;
  float* e_out1   = e_out0 + (size_t)Eu * 64;

  node_kernel<<<(N + NR - 1) / NR, 128, 0, stream>>>(
      s_t, x_t, v_t, dst_lig_x, dst_lig_a, W1, b1, W2, b2,
      node_out, v_out, N);

  edge_kernel<<<(Eu + EB - 1) / EB, 256, 0, stream>>>(
      e_t, x_t, dst_lig_x, dst_lig_e, edge_src, edge_dst, We, be,
      e_out0, e_out1, Eu);
}

// Round 4
// 281.279 us; speedup vs baseline: 17.8126x; 1.9393x over previous
//
#include <hip/hip_runtime.h>
#include <math.h>

typedef short bf16x8 __attribute__((ext_vector_type(8)));
typedef float f32x4 __attribute__((ext_vector_type(4)));

__device__ __forceinline__ float silu_f(float x) {
  return x / (1.0f + __expf(-x));
}
__device__ __forceinline__ unsigned short f2bf(float x) {
  union { float f; unsigned u; } v; v.f = x;
  unsigned r = v.u + 0x7FFFu + ((v.u >> 16) & 1u);   // round-nearest-even
  return (unsigned short)(r >> 16);
}
__device__ __forceinline__ float bf2f(unsigned short h) {
  union { unsigned u; float f; } v; v.u = ((unsigned)h) << 16; return v.f;
}

// ---- prep: build bf16 transposed weights in ws ----
// wet:  [64 cols][96 K]   at ws[0..6144)        (K 85..95 zero)
// w1t:  [128 cols][160 K] at ws[6144..26624)
// w2t:  [128 cols][128 K] at ws[26624..43008)
__global__ __launch_bounds__(256)
void prep_kernel(const float* __restrict__ W1, const float* __restrict__ W2,
                 const float* __restrict__ We, unsigned short* __restrict__ ws)
{
  int i = blockIdx.x * 256 + threadIdx.x;
  if (i < 6144) {
    int col = i / 96, k = i - col * 96;
    float v = (k < 85) ? We[k * 64 + col] : 0.0f;
    ws[i] = f2bf(v);
  }
  int j = i - 6144;
  if (j >= 0 && j < 20480) {
    int col = j / 160, k = j - col * 160;
    ws[6144 + j] = f2bf(W1[k * 128 + col]);
  }
  int l = i - 26624;
  if (l >= 0 && l < 16384) {
    int col = l >> 7, k = l & 127;
    ws[26624 + l] = f2bf(W2[k * 128 + col]);
  }
}

// ---------------- node kernel: node_out + v_out (MFMA) ----------------
// 64 rows/block, 4 waves. A1[64][168] bf16 = [rbf16|a16|s128]+pad.
__global__ __launch_bounds__(256, 4)
void node_kernel(const float* __restrict__ s_t,
                 const float* __restrict__ x_t,
                 const float* __restrict__ v_t,
                 const float* __restrict__ dst_lig_x,
                 const float* __restrict__ dst_lig_a,
                 const unsigned short* __restrict__ w1t, const float* __restrict__ b1,
                 const unsigned short* __restrict__ w2t, const float* __restrict__ b2,
                 float* __restrict__ node_out, float* __restrict__ v_out,
                 int N)
{
  __shared__ unsigned short A1[64][168];   // stride 84 words (%32=20) -> 2-way
  __shared__ unsigned short H [64][136];   // stride 68 words (%32=4)  -> 2-way
  __shared__ float xd[64][4];              // dx,dy,dz,dij
  const int t = threadIdx.x;
  const int row0 = blockIdx.x * 64;
  const int w = t >> 6, lane = t & 63;

  // stage s_t -> A1 cols 32..159 (float4 -> 4 bf16 -> 8B LDS write)
  #pragma unroll
  for (int p = 0; p < 8; ++p) {
    int i = p * 256 + t;
    int row = i >> 5, q = i & 31;
    if (row0 + row < N) {
      const float4 v = *reinterpret_cast<const float4*>(&s_t[(size_t)(row0 + row) * 128 + q * 4]);
      uint2 pk;
      pk.x = f2bf(v.x) | ((unsigned)f2bf(v.y) << 16);
      pk.y = f2bf(v.z) | ((unsigned)f2bf(v.w) << 16);
      *reinterpret_cast<uint2*>(&A1[row][32 + q * 4]) = pk;
    }
  }
  // distances
  if (t < 64) {
    int row = row0 + t;
    if (row < N) {
      float dx = dst_lig_x[row*3+0] - x_t[row*3+0];
      float dy = dst_lig_x[row*3+1] - x_t[row*3+1];
      float dz = dst_lig_x[row*3+2] - x_t[row*3+2];
      float dij = sqrtf(fmaxf(dx*dx + dy*dy + dz*dz, 1e-8f));
      xd[t][0] = dx; xd[t][1] = dy; xd[t][2] = dz; xd[t][3] = dij;
    }
  }
  __syncthreads();
  // rbf + dst_lig_a -> A1 cols 0..31; v_out
  #pragma unroll
  for (int p = 0; p < 4; ++p) {
    int i = p * 256 + t;
    int el = i >> 4, m = i & 15;
    int row = row0 + el;
    if (row < N) {
      float dij = xd[el][3];
      float tt = (dij - 0.66666667f * (float)m) * 1.6f;
      A1[el][m]      = f2bf(__expf(-tt * tt));
      A1[el][16 + m] = f2bf(dst_lig_a[(size_t)row * 16 + m]);
      if (m < 12) {
        float val = (m < 9) ? v_t[(size_t)row * 12 + m] : xd[el][m - 9] / dij;
        __builtin_nontemporal_store(val, &v_out[(size_t)row * 12 + m]);
      }
    }
  }
  __syncthreads();

  const int mb = (w & 1) * 32;   // wave's row base   (2 m-tiles)
  const int nb = (w >> 1) * 64;  // wave's col base   (4 n-tiles)

  // layer 1: K=160, 5 k-steps
  f32x4 acc[2][4] = {};
  #pragma unroll 1
  for (int ks = 0; ks < 5; ++ks) {
    const int ko = ks * 32 + ((lane >> 4) << 3);
    bf16x8 af[2], bfr[4];
    #pragma unroll
    for (int m = 0; m < 2; ++m)
      af[m] = *reinterpret_cast<const bf16x8*>(&A1[mb + m*16 + (lane & 15)][ko]);
    #pragma unroll
    for (int n = 0; n < 4; ++n)
      bfr[n] = *reinterpret_cast<const bf16x8*>(&w1t[(size_t)(nb + n*16 + (lane & 15)) * 160 + ko]);
    #pragma unroll
    for (int m = 0; m < 2; ++m)
      #pragma unroll
      for (int n = 0; n < 4; ++n)
        acc[m][n] = __builtin_amdgcn_mfma_f32_16x16x32_bf16(af[m], bfr[n], acc[m][n], 0, 0, 0);
  }
  // h = silu(acc + b1) -> H (bf16)
  #pragma unroll
  for (int n = 0; n < 4; ++n) {
    float bb = b1[nb + n*16 + (lane & 15)];
    #pragma unroll
    for (int m = 0; m < 2; ++m) {
      int r0 = mb + m*16 + ((lane >> 4) << 2);
      int c  = nb + n*16 + (lane & 15);
      #pragma unroll
      for (int r = 0; r < 4; ++r)
        H[r0 + r][c] = f2bf(silu_f(acc[m][n][r] + bb));
    }
  }
  __syncthreads();

  // layer 2: K=128, 4 k-steps
  f32x4 acc2[2][4] = {};
  #pragma unroll 1
  for (int ks = 0; ks < 4; ++ks) {
    const int ko = ks * 32 + ((lane >> 4) << 3);
    bf16x8 af[2], bfr[4];
    #pragma unroll
    for (int m = 0; m < 2; ++m)
      af[m] = *reinterpret_cast<const bf16x8*>(&H[mb + m*16 + (lane & 15)][ko]);
    #pragma unroll
    for (int n = 0; n < 4; ++n)
      bfr[n] = *reinterpret_cast<const bf16x8*>(&w2t[(size_t)(nb + n*16 + (lane & 15)) * 128 + ko]);
    #pragma unroll
    for (int m = 0; m < 2; ++m)
      #pragma unroll
      for (int n = 0; n < 4; ++n)
        acc2[m][n] = __builtin_amdgcn_mfma_f32_16x16x32_bf16(af[m], bfr[n], acc2[m][n], 0, 0, 0);
  }
  // node_out = s_t + silu(acc2 + b2)
  #pragma unroll
  for (int n = 0; n < 4; ++n) {
    float bb = b2[nb + n*16 + (lane & 15)];
    #pragma unroll
    for (int m = 0; m < 2; ++m) {
      int r0 = mb + m*16 + ((lane >> 4) << 2);
      int c  = nb + n*16 + (lane & 15);
      #pragma unroll
      for (int r = 0; r < 4; ++r) {
        int row = row0 + r0 + r;
        if (row < N) {
          float o = bf2f(A1[r0 + r][32 + c]) + silu_f(acc2[m][n][r] + bb);
          __builtin_nontemporal_store(o, &node_out[(size_t)row * 128 + c]);
        }
      }
    }
  }
}

// ---------------- edge kernel: e_out (MFMA) ----------------
// 64 edges/block, 4 waves. A[64][104] bf16 = [e_u 64 | lig_e 5 | dinp 16 | 0-pad ..95].
__global__ __launch_bounds__(256, 4)
void edge_kernel(const float* __restrict__ e_t,
                 const float* __restrict__ x_t,
                 const float* __restrict__ dst_lig_x,
                 const float* __restrict__ dst_lig_e,
                 const int* __restrict__ edge_src,
                 const int* __restrict__ edge_dst,
                 const unsigned short* __restrict__ wet, const float* __restrict__ be,
                 float* __restrict__ e_out0, float* __restrict__ e_out1,
                 int Eu)
{
  __shared__ unsigned short A[64][104];    // stride 52 words (%32=20) -> 2-way
  __shared__ float dd[64][2];
  const int t = threadIdx.x;
  const int e0 = blockIdx.x * 64;
  const int w = t >> 6, lane = t & 63;

  // e_u -> A cols 0..63 (float2 -> packed bf16x2)
  #pragma unroll
  for (int p = 0; p < 8; ++p) {
    int i = p * 256 + t;
    int row = i >> 5, cp = i & 31;
    if (e0 + row < Eu) {
      const float2 v = *reinterpret_cast<const float2*>(&e_t[(size_t)(e0 + row) * 64 + cp * 2]);
      unsigned pk = f2bf(v.x) | ((unsigned)f2bf(v.y) << 16);
      *reinterpret_cast<unsigned*>(&A[row][cp * 2]) = pk;
    }
  }
  // distances: 64 edges x 2
  if (t < 128) {
    int el = t >> 1, which = t & 1;
    int e = e0 + el;
    if (e < Eu) {
      int su = edge_src[e], du = edge_dst[e];
      const float* base = which ? dst_lig_x : x_t;
      float u0 = base[su*3+0] - base[du*3+0];
      float u1 = base[su*3+1] - base[du*3+1];
      float u2 = base[su*3+2] - base[du*3+2];
      dd[el][which] = sqrtf(fmaxf(u0*u0 + u1*u1 + u2*u2, 1e-8f));
    }
  }
  // dst_lig_e -> cols 64..68
  #pragma unroll
  for (int q = 0; q < 2; ++q) {
    int i = q * 256 + t;
    if (i < 320) {
      int el = i / 5, c = i - el * 5;
      if (e0 + el < Eu) A[el][64 + c] = f2bf(dst_lig_e[(size_t)(e0 + el) * 5 + c]);
    }
  }
  // zero cols 85..95
  #pragma unroll
  for (int q = 0; q < 3; ++q) {
    int i = q * 256 + t;
    if (i < 704) { int el = i / 11, c = i - el * 11; A[el][85 + c] = 0; }
  }
  __syncthreads();
  // d_input -> cols 69..84
  #pragma unroll
  for (int q = 0; q < 4; ++q) {
    int i = q * 256 + t;
    int el = i >> 4, m = i & 15;
    if (e0 + el < Eu) {
      float dt_ = dd[el][0], d1_ = dd[el][1];
      float mu = 0.66666667f * (float)m;
      float a1 = (d1_ - mu) * 1.6f, a2 = (dt_ - mu) * 1.6f;
      A[el][69 + m] = f2bf(__expf(-a1*a1) - __expf(-a2*a2));
    }
  }
  __syncthreads();

  const int mb = (w & 1) * 32;   // 2 m-tiles
  const int nb = (w >> 1) * 32;  // 2 n-tiles

  f32x4 acc[2][2] = {};
  #pragma unroll 1
  for (int ks = 0; ks < 3; ++ks) {
    const int ko = ks * 32 + ((lane >> 4) << 3);
    bf16x8 af[2], bfr[2];
    #pragma unroll
    for (int m = 0; m < 2; ++m)
      af[m] = *reinterpret_cast<const bf16x8*>(&A[mb + m*16 + (lane & 15)][ko]);
    #pragma unroll
    for (int n = 0; n < 2; ++n)
      bfr[n] = *reinterpret_cast<const bf16x8*>(&wet[(size_t)(nb + n*16 + (lane & 15)) * 96 + ko]);
    #pragma unroll
    for (int m = 0; m < 2; ++m)
      #pragma unroll
      for (int n = 0; n < 2; ++n)
        acc[m][n] = __builtin_amdgcn_mfma_f32_16x16x32_bf16(af[m], bfr[n], acc[m][n], 0, 0, 0);
  }
  #pragma unroll
  for (int n = 0; n < 2; ++n) {
    float bb = be[nb + n*16 + (lane & 15)];
    #pragma unroll
    for (int m = 0; m < 2; ++m) {
      int r0 = mb + m*16 + ((lane >> 4) << 2);
      int c  = nb + n*16 + (lane & 15);
      #pragma unroll
      for (int r = 0; r < 4; ++r) {
        size_t eidx = (size_t)e0 + r0 + r;
        if ((int)eidx < Eu) {
          float feat = bf2f(A[r0 + r][c]) + silu_f(acc[m][n][r] + bb);
          __builtin_nontemporal_store(feat, &e_out0[eidx * 64 + c]);
          __builtin_nontemporal_store(feat, &e_out1[eidx * 64 + c]);
        }
      }
    }
  }
}

extern "C" void kernel_launch(void* const* d_in, const int* in_sizes, int n_in,
                              void* d_out, int out_size, void* d_ws, size_t ws_size,
                              hipStream_t stream) {
  const float* s_t       = (const float*)d_in[0];
  const float* x_t       = (const float*)d_in[1];
  const float* v_t       = (const float*)d_in[2];
  const float* e_t       = (const float*)d_in[3];
  const float* dst_lig_x = (const float*)d_in[4];
  const float* dst_lig_a = (const float*)d_in[5];
  const float* dst_lig_e = (const float*)d_in[6];
  const int*   edge_src  = (const int*)d_in[7];
  const int*   edge_dst  = (const int*)d_in[8];
  const float* W1        = (const float*)d_in[9];
  const float* b1        = (const float*)d_in[10];
  const float* W2        = (const float*)d_in[11];
  const float* b2        = (const float*)d_in[12];
  const float* We        = (const float*)d_in[13];
  const float* be        = (const float*)d_in[14];

  const int N  = in_sizes[0] / 128;       // 100000
  const int Eu = in_sizes[3] / 128;       // 800000

  float* out      = (float*)d_out;
  float* node_out = out;
  float* v_out    = out + (size_t)N * 128;
  float* e_out0   = v_out + (size_t)N * 12;
  float* e_out1   = e_out0 + (size_t)Eu * 64;

  unsigned short* wsp = (unsigned short*)d_ws;
  unsigned short* wet = wsp;            // 6144
  unsigned short* w1t = wsp + 6144;     // 20480
  unsigned short* w2t = wsp + 26624;    // 16384

  prep_kernel<<<168, 256, 0, stream>>>(W1, W2, We, wsp);

  node_kernel<<<(N + 63) / 64, 256, 0, stream>>>(
      s_t, x_t, v_t, dst_lig_x, dst_lig_a, w1t, b1, w2t, b2,
      node_out, v_out, N);

  edge_kernel<<<(Eu + 63) / 64, 256, 0, stream>>>(
      e_t, x_t, dst_lig_x, dst_lig_e, edge_src, edge_dst, wet, be,
      e_out0, e_out1, Eu);
}

// Round 6
// 255.671 us; speedup vs baseline: 19.5967x; 1.1002x over previous
//
#include <hip/hip_runtime.h>
#include <math.h>

typedef short bf16x8 __attribute__((ext_vector_type(8)));
typedef float f32x4 __attribute__((ext_vector_type(4)));
typedef float fvec4 __attribute__((ext_vector_type(4)));   // for nontemporal vector loads

#define EBK 128   // edges per block (edge kernel)

__device__ __forceinline__ float silu_f(float x) {
  return x / (1.0f + __expf(-x));
}
__device__ __forceinline__ unsigned short f2bf(float x) {
  union { float f; unsigned u; } v; v.f = x;
  unsigned r = v.u + 0x7FFFu + ((v.u >> 16) & 1u);   // round-nearest-even
  return (unsigned short)(r >> 16);
}
__device__ __forceinline__ float bf2f(unsigned short h) {
  union { unsigned u; float f; } v; v.u = ((unsigned)h) << 16; return v.f;
}

// ---- prep: build bf16 transposed weights in ws ----
// wet:  [64 cols][96 K]   at ws[0..6144)        (K 85..95 zero)
// w1t:  [128 cols][160 K] at ws[6144..26624)
// w2t:  [128 cols][128 K] at ws[26624..43008)
__global__ __launch_bounds__(256)
void prep_kernel(const float* __restrict__ W1, const float* __restrict__ W2,
                 const float* __restrict__ We, unsigned short* __restrict__ ws)
{
  int i = blockIdx.x * 256 + threadIdx.x;
  if (i < 6144) {
    int col = i / 96, k = i - col * 96;
    float v = (k < 85) ? We[k * 64 + col] : 0.0f;
    ws[i] = f2bf(v);
  }
  int j = i - 6144;
  if (j >= 0 && j < 20480) {
    int col = j / 160, k = j - col * 160;
    ws[6144 + j] = f2bf(W1[k * 128 + col]);
  }
  int l = i - 26624;
  if (l >= 0 && l < 16384) {
    int col = l >> 7, k = l & 127;
    ws[26624 + l] = f2bf(W2[k * 128 + col]);
  }
}

// ---------------- node kernel: node_out + v_out (MFMA) ----------------
// 64 rows/block, 4 waves. A1[64][168] bf16 = [rbf16|a16|s128]+pad.
// Single pre-GEMM sync: distance is recomputed per-lane (broadcast loads).
__global__ __launch_bounds__(256, 4)
void node_kernel(const float* __restrict__ s_t,
                 const float* __restrict__ x_t,
                 const float* __restrict__ v_t,
                 const float* __restrict__ dst_lig_x,
                 const float* __restrict__ dst_lig_a,
                 const unsigned short* __restrict__ w1t, const float* __restrict__ b1,
                 const unsigned short* __restrict__ w2t, const float* __restrict__ b2,
                 float* __restrict__ node_out, float* __restrict__ v_out,
                 int N)
{
  __shared__ unsigned short A1[64][168];   // stride 84 words (%32=20) -> 2-way
  __shared__ unsigned short H [64][136];   // stride 68 words (%32=4)  -> 2-way
  const int t = threadIdx.x;
  const int row0 = blockIdx.x * 64;
  const int w = t >> 6, lane = t & 63;

  // stage s_t -> A1 cols 32..159 (float4 -> packed bf16; wave reads 1KB contig)
  #pragma unroll
  for (int p = 0; p < 8; ++p) {
    int i = p * 256 + t;
    int row = i >> 5, q = i & 31;
    if (row0 + row < N) {
      const fvec4 v = __builtin_nontemporal_load(
          reinterpret_cast<const fvec4*>(&s_t[(size_t)(row0 + row) * 128 + q * 4]));
      uint2 pk;
      pk.x = f2bf(v.x) | ((unsigned)f2bf(v.y) << 16);
      pk.y = f2bf(v.z) | ((unsigned)f2bf(v.w) << 16);
      *reinterpret_cast<uint2*>(&A1[row][32 + q * 4]) = pk;
    }
  }
  // rbf + dst_lig_a -> A1 cols 0..31; v_out. 16 lanes/row recompute the
  // distance from the same addresses (broadcast) -- no sync needed.
  #pragma unroll
  for (int p = 0; p < 4; ++p) {
    int i = p * 256 + t;
    int el = i >> 4, m = i & 15;
    int row = row0 + el;
    if (row < N) {
      float dx = dst_lig_x[row*3+0] - x_t[row*3+0];
      float dy = dst_lig_x[row*3+1] - x_t[row*3+1];
      float dz = dst_lig_x[row*3+2] - x_t[row*3+2];
      float dij = sqrtf(fmaxf(dx*dx + dy*dy + dz*dz, 1e-8f));
      float tt = (dij - 0.66666667f * (float)m) * 1.6f;
      A1[el][m]      = f2bf(__expf(-tt * tt));
      A1[el][16 + m] = f2bf(dst_lig_a[(size_t)row * 16 + m]);
      if (m < 12) {
        float val;
        if (m < 9)       val = v_t[(size_t)row * 12 + m];
        else if (m == 9) val = dx / dij;
        else if (m == 10)val = dy / dij;
        else             val = dz / dij;
        __builtin_nontemporal_store(val, &v_out[(size_t)row * 12 + m]);
      }
    }
  }
  __syncthreads();

  const int mb = (w & 1) * 32;   // 2 m-tiles
  const int nb = (w >> 1) * 64;  // 4 n-tiles

  // layer 1: K=160, 5 k-steps
  f32x4 acc[2][4] = {};
  #pragma unroll 1
  for (int ks = 0; ks < 5; ++ks) {
    const int ko = ks * 32 + ((lane >> 4) << 3);
    bf16x8 af[2], bfr[4];
    #pragma unroll
    for (int m = 0; m < 2; ++m)
      af[m] = *reinterpret_cast<const bf16x8*>(&A1[mb + m*16 + (lane & 15)][ko]);
    #pragma unroll
    for (int n = 0; n < 4; ++n)
      bfr[n] = *reinterpret_cast<const bf16x8*>(&w1t[(size_t)(nb + n*16 + (lane & 15)) * 160 + ko]);
    #pragma unroll
    for (int m = 0; m < 2; ++m)
      #pragma unroll
      for (int n = 0; n < 4; ++n)
        acc[m][n] = __builtin_amdgcn_mfma_f32_16x16x32_bf16(af[m], bfr[n], acc[m][n], 0, 0, 0);
  }
  #pragma unroll
  for (int n = 0; n < 4; ++n) {
    float bb = b1[nb + n*16 + (lane & 15)];
    #pragma unroll
    for (int m = 0; m < 2; ++m) {
      int r0 = mb + m*16 + ((lane >> 4) << 2);
      int c  = nb + n*16 + (lane & 15);
      #pragma unroll
      for (int r = 0; r < 4; ++r)
        H[r0 + r][c] = f2bf(silu_f(acc[m][n][r] + bb));
    }
  }
  __syncthreads();

  // layer 2: K=128, 4 k-steps
  f32x4 acc2[2][4] = {};
  #pragma unroll 1
  for (int ks = 0; ks < 4; ++ks) {
    const int ko = ks * 32 + ((lane >> 4) << 3);
    bf16x8 af[2], bfr[4];
    #pragma unroll
    for (int m = 0; m < 2; ++m)
      af[m] = *reinterpret_cast<const bf16x8*>(&H[mb + m*16 + (lane & 15)][ko]);
    #pragma unroll
    for (int n = 0; n < 4; ++n)
      bfr[n] = *reinterpret_cast<const bf16x8*>(&w2t[(size_t)(nb + n*16 + (lane & 15)) * 128 + ko]);
    #pragma unroll
    for (int m = 0; m < 2; ++m)
      #pragma unroll
      for (int n = 0; n < 4; ++n)
        acc2[m][n] = __builtin_amdgcn_mfma_f32_16x16x32_bf16(af[m], bfr[n], acc2[m][n], 0, 0, 0);
  }
  #pragma unroll
  for (int n = 0; n < 4; ++n) {
    float bb = b2[nb + n*16 + (lane & 15)];
    #pragma unroll
    for (int m = 0; m < 2; ++m) {
      int r0 = mb + m*16 + ((lane >> 4) << 2);
      int c  = nb + n*16 + (lane & 15);
      #pragma unroll
      for (int r = 0; r < 4; ++r) {
        int row = row0 + r0 + r;
        if (row < N) {
          float o = bf2f(A1[r0 + r][32 + c]) + silu_f(acc2[m][n][r] + bb);
          __builtin_nontemporal_store(o, &node_out[(size_t)row * 128 + c]);
        }
      }
    }
  }
}

// ---------------- edge kernel: e_out (MFMA) ----------------
// 128 edges/block, 4 waves; wave w owns rows w*32..w*32+31 (2 m-tiles x 4 n-tiles).
// A[128][104] bf16 = [e_u 64 | lig_e 5 | dinp 16 | 0-pad ..95]. One sync total:
// distances live in registers, exchanged pairwise via shfl_xor.
__global__ __launch_bounds__(256, 4)
void edge_kernel(const float* __restrict__ e_t,
                 const float* __restrict__ x_t,
                 const float* __restrict__ dst_lig_x,
                 const float* __restrict__ dst_lig_e,
                 const int* __restrict__ edge_src,
                 const int* __restrict__ edge_dst,
                 const unsigned short* __restrict__ wet, const float* __restrict__ be,
                 float* __restrict__ e_out0, float* __restrict__ e_out1,
                 int Eu)
{
  __shared__ unsigned short A[EBK][104];   // stride 52 words (%32=20) -> 2-way
  const int t = threadIdx.x;
  const int e0 = blockIdx.x * EBK;
  const int w = t >> 6, lane = t & 63;

  // e_u -> A cols 0..63 (float4/lane; wave reads 1KB contiguous)
  #pragma unroll
  for (int p = 0; p < 8; ++p) {
    int i = p * 256 + t;
    int row = i >> 4, cq = i & 15;
    if (e0 + row < Eu) {
      const fvec4 v = __builtin_nontemporal_load(
          reinterpret_cast<const fvec4*>(&e_t[(size_t)(e0 + row) * 64 + cq * 4]));
      uint2 pk;
      pk.x = f2bf(v.x) | ((unsigned)f2bf(v.y) << 16);
      pk.y = f2bf(v.z) | ((unsigned)f2bf(v.w) << 16);
      *reinterpret_cast<uint2*>(&A[row][cq * 4]) = pk;
    }
  }
  // distances + d_input: 256 threads = 128 edges x 2; pair lanes swap via shfl
  {
    const int el = t >> 1, which = t & 1;
    const int e = e0 + el;
    float dcur = 0.0f;
    if (e < Eu) {
      int su = edge_src[e], du = edge_dst[e];
      const float* base = which ? dst_lig_x : x_t;
      float u0 = base[su*3+0] - base[du*3+0];
      float u1 = base[su*3+1] - base[du*3+1];
      float u2 = base[su*3+2] - base[du*3+2];
      dcur = sqrtf(fmaxf(u0*u0 + u1*u1 + u2*u2, 1e-8f));
    }
    float doth = __shfl_xor(dcur, 1);
    float dt_ = which ? doth : dcur;
    float d1_ = which ? dcur : doth;
    if (e < Eu) {
      #pragma unroll
      for (int q = 0; q < 8; ++q) {
        int m = which * 8 + q;
        float mu = 0.66666667f * (float)m;
        float a1 = (d1_ - mu) * 1.6f, a2 = (dt_ - mu) * 1.6f;
        A[el][69 + m] = f2bf(__expf(-a1*a1) - __expf(-a2*a2));
      }
    }
  }
  // dst_lig_e -> cols 64..68 (128*5 = 640 tasks)
  #pragma unroll
  for (int q = 0; q < 3; ++q) {
    int i = q * 256 + t;
    if (i < EBK * 5) {
      int el = i / 5, c = i - el * 5;
      if (e0 + el < Eu) A[el][64 + c] = f2bf(dst_lig_e[(size_t)(e0 + el) * 5 + c]);
    }
  }
  // zero cols 85..95 (128*11 = 1408 tasks)
  #pragma unroll
  for (int q = 0; q < 6; ++q) {
    int i = q * 256 + t;
    if (i < EBK * 11) { int el = i / 11, c = i - el * 11; A[el][85 + c] = 0; }
  }
  __syncthreads();

  const int mb = w * 32;   // 2 m-tiles per wave, all 4 n-tiles

  f32x4 acc[2][4] = {};
  #pragma unroll 1
  for (int ks = 0; ks < 3; ++ks) {
    const int ko = ks * 32 + ((lane >> 4) << 3);
    bf16x8 af[2], bfr[4];
    #pragma unroll
    for (int m = 0; m < 2; ++m)
      af[m] = *reinterpret_cast<const bf16x8*>(&A[mb + m*16 + (lane & 15)][ko]);
    #pragma unroll
    for (int n = 0; n < 4; ++n)
      bfr[n] = *reinterpret_cast<const bf16x8*>(&wet[(size_t)(n*16 + (lane & 15)) * 96 + ko]);
    #pragma unroll
    for (int m = 0; m < 2; ++m)
      #pragma unroll
      for (int n = 0; n < 4; ++n)
        acc[m][n] = __builtin_amdgcn_mfma_f32_16x16x32_bf16(af[m], bfr[n], acc[m][n], 0, 0, 0);
  }
  #pragma unroll
  for (int n = 0; n < 4; ++n) {
    float bb = be[n*16 + (lane & 15)];
    #pragma unroll
    for (int m = 0; m < 2; ++m) {
      int r0 = mb + m*16 + ((lane >> 4) << 2);
      int c  = n*16 + (lane & 15);
      #pragma unroll
      for (int r = 0; r < 4; ++r) {
        size_t eidx = (size_t)e0 + r0 + r;
        if ((int)eidx < Eu) {
          float feat = bf2f(A[r0 + r][c]) + silu_f(acc[m][n][r] + bb);
          __builtin_nontemporal_store(feat, &e_out0[eidx * 64 + c]);
          __builtin_nontemporal_store(feat, &e_out1[eidx * 64 + c]);
        }
      }
    }
  }
}

extern "C" void kernel_launch(void* const* d_in, const int* in_sizes, int n_in,
                              void* d_out, int out_size, void* d_ws, size_t ws_size,
                              hipStream_t stream) {
  const float* s_t       = (const float*)d_in[0];
  const float* x_t       = (const float*)d_in[1];
  const float* v_t       = (const float*)d_in[2];
  const float* e_t       = (const float*)d_in[3];
  const float* dst_lig_x = (const float*)d_in[4];
  const float* dst_lig_a = (const float*)d_in[5];
  const float* dst_lig_e = (const float*)d_in[6];
  const int*   edge_src  = (const int*)d_in[7];
  const int*   edge_dst  = (const int*)d_in[8];
  const float* W1        = (const float*)d_in[9];
  const float* b1        = (const float*)d_in[10];
  const float* W2        = (const float*)d_in[11];
  const float* b2        = (const float*)d_in[12];
  const float* We        = (const float*)d_in[13];
  const float* be        = (const float*)d_in[14];

  const int N  = in_sizes[0] / 128;       // 100000
  const int Eu = in_sizes[3] / 128;       // 800000

  float* out      = (float*)d_out;
  float* node_out = out;
  float* v_out    = out + (size_t)N * 128;
  float* e_out0   = v_out + (size_t)N * 12;
  float* e_out1   = e_out0 + (size_t)Eu * 64;

  unsigned short* wsp = (unsigned short*)d_ws;
  unsigned short* wet = wsp;            // 6144
  unsigned short* w1t = wsp + 6144;     // 20480
  unsigned short* w2t = wsp + 26624;    // 16384

  prep_kernel<<<168, 256, 0, stream>>>(W1, W2, We, wsp);

  edge_kernel<<<(Eu + EBK - 1) / EBK, 256, 0, stream>>>(
      e_t, x_t, dst_lig_x, dst_lig_e, edge_src, edge_dst, wet, be,
      e_out0, e_out1, Eu);

  node_kernel<<<(N + 63) / 64, 256, 0, stream>>>(
      s_t, x_t, v_t, dst_lig_x, dst_lig_a, w1t, b1, w2t, b2,
      node_out, v_out, N);
}